// Round 9
// baseline (1892.104 us; speedup 1.0000x reference)
//
#include <hip/hip_runtime.h>
#include <hip/hip_bf16.h>

// Sizes
#define U_    1200
#define E_    620
#define B_    128
#define T_    64
#define N3    3600           // 3*U
#define NP    3712           // padded 3U = 29*128
#define KE    640            // padded E  = 10*64
#define KU    1216           // padded U  = 19*64
#define WIN   16             // xproj window (scan steps per window GEMM)
#define LN_EPS 1e-3f

#define GBLK  232            // GEMM blocks per launch (8 xcd * 29)
#define UBLK  128            // update blocks per launch
#define TBLK  (GBLK + UBLK)  // 360

typedef __attribute__((ext_vector_type(8))) short short8;
typedef __attribute__((ext_vector_type(4))) float f32x4;
typedef _Float16 f16;
typedef __attribute__((ext_vector_type(8))) _Float16 half8;

// ---------------- workspace layout (bytes) ----------------
constexpr size_t OFF_EMBH  = 0;                                   // bf16 [8192][KE] hi
constexpr size_t SZ_EMB    = (size_t)8192 * KE * 2;
constexpr size_t OFF_EMBL  = OFF_EMBH + SZ_EMB;
constexpr size_t OFF_KTH   = OFF_EMBL + SZ_EMB;                   // bf16 [2][NP][KE] hi
constexpr size_t SZ_KT     = (size_t)2 * NP * KE * 2;
constexpr size_t OFF_KTL   = OFF_KTH + SZ_KT;
constexpr size_t OFF_RKF   = OFF_KTL + SZ_KT;                     // f16 [2][NP][KU]
constexpr size_t SZ_RKF    = (size_t)2 * NP * KU * 2;
constexpr size_t OFF_XPW   = OFF_RKF + SZ_RKF;                    // f32 [2][WIN][B][NP]
constexpr size_t SZ_XPW    = (size_t)2 * WIN * B_ * NP * 4;
constexpr size_t OFF_INNER = OFF_XPW + SZ_XPW;                    // f32 [2d*2kp][B][NP]
constexpr size_t SZ_INNER  = (size_t)4 * B_ * NP * 4;
constexpr size_t OFF_HLN   = OFF_INNER + SZ_INNER;                // f32 [2][B][U]
constexpr size_t SZ_HLN    = (size_t)2 * B_ * U_ * 4;
constexpr size_t OFF_HLFH  = OFF_HLN + SZ_HLN;                    // f16 [2][B][KU] hi
constexpr size_t SZ_HLF    = (size_t)2 * B_ * KU * 2;
constexpr size_t OFF_HLFL  = OFF_HLFH + SZ_HLF;

__device__ inline void lds_load16(const void* g, void* l) {
  __builtin_amdgcn_global_load_lds(
      (const __attribute__((address_space(1))) unsigned int*)g,
      (__attribute__((address_space(3))) unsigned int*)l, 16, 0, 0);
}

__device__ inline float sigmf(float x) { return 1.f / (1.f + expf(-x)); }

// Swizzle helpers (verified r6-r8: 0 bank conflicts). LDS tiles [rows][64
// 2B-elems]; stage pre-swizzles the GLOBAL column group, read XORs in-row.
__device__ inline int swz_scol(int tid) {
  return (((tid & 7) ^ ((tid >> 3) & 7)) << 3);
}
__device__ inline int swz_off(int row, int kk, int lane) {
  return row * 64 + ((kk * 32 + ((lane >> 4) << 3)) ^ ((row & 7) << 3));
}

// ---------------- K1: embedding gather + tanh (fp32 out + hi/lo bf16) -----
__global__ __launch_bounds__(256)
void embed_kernel(const int* __restrict__ sent, const float* __restrict__ embed,
                  float* __restrict__ out_emb,
                  __hip_bfloat16* __restrict__ embH, __hip_bfloat16* __restrict__ embL) {
  const int row = blockIdx.x;                 // b*T + t
  const int idx = sent[row];
  const float* src = embed + (size_t)idx * E_;
  for (int e = threadIdx.x; e < KE; e += 256) {
    float v = 0.f;
    if (e < E_) {
      v = tanhf(src[e]);
      out_emb[(size_t)row * E_ + e] = v;
    }
    const __hip_bfloat16 hi = __float2bfloat16(v);
    embH[(size_t)row * KE + e] = hi;
    embL[(size_t)row * KE + e] = __float2bfloat16(v - __bfloat162float(hi));
  }
}

// ---------------- K2a: transpose+cast [K][3600]f32 -> [NP][Kp] hi/lo bf16 --
__global__ __launch_bounds__(256)
void transpose_cast(const float* __restrict__ W0, const float* __restrict__ W1,
                    __hip_bfloat16* __restrict__ WtHi, __hip_bfloat16* __restrict__ WtLo,
                    int Kreal, int Kp) {
  const int d = blockIdx.z;
  const float* W = d ? W1 : W0;
  __hip_bfloat16* dstH = WtHi + (size_t)d * NP * Kp;
  __hip_bfloat16* dstL = WtLo + (size_t)d * NP * Kp;
  __shared__ float tile[32][33];
  const int n0 = blockIdx.x * 32, k0 = blockIdx.y * 32;
  const int tx = threadIdx.x, ty = threadIdx.y;   // 32 x 8
#pragma unroll
  for (int i = 0; i < 32; i += 8) {
    const int k = k0 + ty + i, n = n0 + tx;
    tile[ty + i][tx] = (k < Kreal && n < N3) ? W[(size_t)k * N3 + n] : 0.f;
  }
  __syncthreads();
#pragma unroll
  for (int i = 0; i < 32; i += 8) {
    const int n = n0 + ty + i, k = k0 + tx;
    const float v = tile[tx][ty + i];
    const __hip_bfloat16 hi = __float2bfloat16(v);
    dstH[(size_t)n * Kp + k] = hi;
    dstL[(size_t)n * Kp + k] = __float2bfloat16(v - __bfloat162float(hi));
  }
}

// ---------------- K2b: transpose+cast [K][3600]f32 -> [NP][Kp] f16 --------
__global__ __launch_bounds__(256)
void transpose_cast_f16(const float* __restrict__ W0, const float* __restrict__ W1,
                        f16* __restrict__ Wt, int Kreal, int Kp) {
  const int d = blockIdx.z;
  const float* W = d ? W1 : W0;
  f16* dst = Wt + (size_t)d * NP * Kp;
  __shared__ float tile[32][33];
  const int n0 = blockIdx.x * 32, k0 = blockIdx.y * 32;
  const int tx = threadIdx.x, ty = threadIdx.y;   // 32 x 8
#pragma unroll
  for (int i = 0; i < 32; i += 8) {
    const int k = k0 + ty + i, n = n0 + tx;
    tile[ty + i][tx] = (k < Kreal && n < N3) ? W[(size_t)k * N3 + n] : 0.f;
  }
  __syncthreads();
#pragma unroll
  for (int i = 0; i < 32; i += 8) {
    const int n = n0 + ty + i, k = k0 + tx;
    dst[(size_t)n * Kp + k] = (f16)tile[tx][ty + i];
  }
}

// ---------------- K4: init h_ln = LN(0) = beta ----------------
__global__ __launch_bounds__(256)
void init_hln(const float* __restrict__ fw_b0, const float* __restrict__ bw_b0,
              float* __restrict__ hln, f16* __restrict__ hlfH, f16* __restrict__ hlfL) {
  const int idx = blockIdx.x * 256 + threadIdx.x;   // [2*128*KU]
  if (idx >= 2 * B_ * KU) return;
  const int k = idx % KU;
  const int rowd = idx / KU;
  const int d = rowd >> 7;
  float v = 0.f;
  if (k < U_) {
    v = (d ? bw_b0 : fw_b0)[k];
    hln[(size_t)rowd * U_ + k] = v;
  }
  const f16 hi = (f16)v;
  hlfH[idx] = hi;
  hlfL[idx] = (f16)(v - (float)hi);
}

// ---------------- window GEMM: x+ib for WIN scan steps, f32 out -----------
// T3 dbuf: stage(next) issued BEFORE compute(cur); ONE barrier per K-step.
// LDS 128 KB (1 block/CU) -> stage latency hides under ds_read+MFMA.
__global__ __launch_bounds__(256)
void xwin_gemm(const __hip_bfloat16* __restrict__ embH, const __hip_bfloat16* __restrict__ embL,
               const __hip_bfloat16* __restrict__ kTH, const __hip_bfloat16* __restrict__ kTL,
               const float* __restrict__ fw_bias, const float* __restrict__ bw_bias,
               float* __restrict__ xpw, int w0) {
  constexpr int BM = 128, BN = 128, BK = 64;
  constexpr int WM = 64, WN = 64, FM = 4, FN = 4;
  const int bid = blockIdx.x;
  const int w = (bid & 7) * 116 + (bid >> 3);     // bijective: 928 = 8*116
  const int d = w / 464;
  const int q = w % 464;
  const int nt = q / 16, mt = q % 16;
  const int m0 = mt * BM;
  const int n0 = nt * BN;

  const __hip_bfloat16* BH = kTH + (size_t)d * NP * KE;
  const __hip_bfloat16* BL = kTL + (size_t)d * NP * KE;

  const int tid = threadIdx.x;
  const int lane = tid & 63;
  const int wid = tid >> 6;
  const int wr = wid >> 1, wc = wid & 1;

  // 2 bufs x {A hi 8192, A lo 8192, B hi 8192, B lo 8192} bf16 = 128 KB
  __shared__ __align__(16) __hip_bfloat16 xs[65536];

  f32x4 acc[FM][FN] = {};

  const int srow = tid >> 3;
  const int scol = swz_scol(tid);

#define XSTG(buf_, ks_)                                                        \
  {                                                                            \
    const int k0s = (ks_) * BK;                                                \
    __hip_bfloat16* base = xs + (buf_) * 32768;                                \
    _Pragma("unroll")                                                          \
    for (int it = 0; it < 4; ++it) {                                           \
      const int row = m0 + it * 32 + srow;                                     \
      const int b = row & 127, sr = row >> 7;                                  \
      const int txi = d ? (T_ - 1 - (w0 + sr)) : (w0 + sr);                    \
      const size_t goff = (size_t)(b * T_ + txi) * KE + k0s + scol;            \
      lds_load16(embH + goff, base + it * 2048 + tid * 8);                     \
      lds_load16(embL + goff, base + 8192 + it * 2048 + tid * 8);              \
    }                                                                          \
    _Pragma("unroll")                                                          \
    for (int it = 0; it < 4; ++it) {                                           \
      const size_t goff = (size_t)(n0 + it * 32 + srow) * KE + k0s + scol;     \
      lds_load16(BH + goff, base + 16384 + it * 2048 + tid * 8);               \
      lds_load16(BL + goff, base + 24576 + it * 2048 + tid * 8);               \
    }                                                                          \
  }

  XSTG(0, 0)
  __syncthreads();
  int cur = 0;
  for (int ks = 0; ks < KE / BK; ++ks) {
    if (ks + 1 < KE / BK) XSTG(cur ^ 1, ks + 1)
    const __hip_bfloat16* AH = xs + cur * 32768;
    const __hip_bfloat16* AL = AH + 8192;
    const __hip_bfloat16* BHs = AH + 16384;
    const __hip_bfloat16* BLs = AH + 24576;
#pragma unroll
    for (int kk = 0; kk < 2; ++kk) {
      short8 ah[FM], al[FM], bh[FN], bl[FN];
#pragma unroll
      for (int mi = 0; mi < FM; ++mi) {
        const int row = wr * WM + mi * 16 + (lane & 15);
        const int off = swz_off(row, kk, lane);
        ah[mi] = *(const short8*)(AH + off);
        al[mi] = *(const short8*)(AL + off);
      }
#pragma unroll
      for (int ni = 0; ni < FN; ++ni) {
        const int row = wc * WN + ni * 16 + (lane & 15);
        const int off = swz_off(row, kk, lane);
        bh[ni] = *(const short8*)(BHs + off);
        bl[ni] = *(const short8*)(BLs + off);
      }
#pragma unroll
      for (int mi = 0; mi < FM; ++mi)
#pragma unroll
        for (int ni = 0; ni < FN; ++ni) {
          acc[mi][ni] = __builtin_amdgcn_mfma_f32_16x16x32_bf16(ah[mi], bh[ni], acc[mi][ni], 0, 0, 0);
          acc[mi][ni] = __builtin_amdgcn_mfma_f32_16x16x32_bf16(ah[mi], bl[ni], acc[mi][ni], 0, 0, 0);
          acc[mi][ni] = __builtin_amdgcn_mfma_f32_16x16x32_bf16(al[mi], bh[ni], acc[mi][ni], 0, 0, 0);
        }
    }
    __syncthreads();
    cur ^= 1;
  }
#undef XSTG

  const float* ib = d ? bw_bias : fw_bias;
#pragma unroll
  for (int mi = 0; mi < FM; ++mi)
#pragma unroll
    for (int ni = 0; ni < FN; ++ni) {
      const int gc = n0 + wc * WN + ni * 16 + (lane & 15);
      const float bv = (gc < N3) ? ib[gc] : 0.f;
      const int gr0 = m0 + wr * WM + mi * 16 + ((lane >> 4) << 2);
#pragma unroll
      for (int j = 0; j < 4; ++j) {
        const int gr = gr0 + j;
        const int b = gr & 127, srel = gr >> 7;
        const size_t off = ((size_t)(d * WIN + srel) * B_ + b) * NP + gc;
        xpw[off] = acc[mi][ni][j] + bv;
      }
    }
}

// ---------------- block-wide 2-value sum reduction ----------------
__device__ inline void breduce2(float& a, float& b, float* red, int tid) {
#pragma unroll
  for (int off = 32; off; off >>= 1) {
    a += __shfl_down(a, off, 64);
    b += __shfl_down(b, off, 64);
  }
  const int w = tid >> 6;
  __syncthreads();
  if ((tid & 63) == 0) { red[w] = a; red[4 + w] = b; }
  __syncthreads();
  a = red[0] + red[1] + red[2] + red[3];
  b = red[4] + red[5] + red[6] + red[7];
}

// ---------------- fused scan step: GEMM(dG,t) || UPDATE(dU,tU) ------------
// GEMM [0,232): rec = h_ln @ rkernel^T; A = f16 hi/lo (2 MFMA terms),
// W = f16 single (18 MB both dirs, L2-resident, XCD-pinned). T3 dbuf:
// stage(next) before compute(cur), ONE barrier per K-step. split-K2.
// Update [232,360): other direction's step (dep crosses launch boundary).
__global__ __launch_bounds__(256)
void step_fused(const f16* __restrict__ rkF,
                f16* __restrict__ hlfH, f16* __restrict__ hlfL,
                float* __restrict__ hln, float* __restrict__ inner,
                const float* __restrict__ xpw,
                const float* __restrict__ fw_bias, const float* __restrict__ bw_bias,
                const float* __restrict__ fw_ln0g, const float* __restrict__ fw_ln0b,
                const float* __restrict__ fw_ln3g, const float* __restrict__ fw_ln3b,
                const float* __restrict__ bw_ln0g, const float* __restrict__ bw_ln0b,
                const float* __restrict__ bw_ln3g, const float* __restrict__ bw_ln3b,
                float* __restrict__ out_tv,
                int dG, int doG, int dU, int tU, int doU) {
  // 2 bufs x {A hi 4096, A lo 4096, W 4096} f16 = 48 KB
  __shared__ __align__(16) f16 smem[24576];
  __shared__ float red[8];

  const int bid = blockIdx.x;
  const int tid = threadIdx.x;

  if (bid < GBLK) {
    // ================= GEMM part =================
    if (!doG) return;
    const int x  = bid & 7;            // ~xcd: (kp, nh, m)
    const int kp = x >> 2;             // K half
    const int nh = (x >> 1) & 1;       // nt half
    const int m  = x & 1;
    const int i  = bid >> 3;           // 0..28
    const int nt = i + 29 * nh;        // 0..57
    const int ks0 = kp ? 10 : 0;
    const int ks1 = kp ? 19 : 10;
    const int m0 = m * 64;
    const int n0 = nt * 64;

    const int lane = tid & 63;
    const int wid = tid >> 6;
    const int wr = wid >> 1, wc = wid & 1;

    const f16* WF = rkF + (size_t)dG * NP * KU;

    f32x4 acc[2][2] = {};
    const int srow = tid >> 3;
    const int scol = swz_scol(tid);

#define STG(buf_, ks_)                                                         \
  {                                                                            \
    const int k0s = (ks_) * 64;                                                \
    f16* base = smem + (buf_) * 12288;                                         \
    _Pragma("unroll")                                                          \
    for (int it = 0; it < 2; ++it) {                                           \
      const size_t ga = (size_t)(dG * B_ + m0 + it * 32 + srow) * KU + k0s + scol; \
      lds_load16(hlfH + ga, base + it * 2048 + tid * 8);                       \
      lds_load16(hlfL + ga, base + 4096 + it * 2048 + tid * 8);                \
      const size_t gb = (size_t)(n0 + it * 32 + srow) * KU + k0s + scol;       \
      lds_load16(WF + gb, base + 8192 + it * 2048 + tid * 8);                  \
    }                                                                          \
  }

    STG(0, ks0)
    __syncthreads();
    int cur = 0;
    for (int ks = ks0; ks < ks1; ++ks) {
      if (ks + 1 < ks1) STG(cur ^ 1, ks + 1)
      const f16* AH = smem + cur * 12288;
      const f16* AL = AH + 4096;
      const f16* BW = AH + 8192;
#pragma unroll
      for (int kk = 0; kk < 2; ++kk) {
        half8 ah[2], al[2], bv[2];
#pragma unroll
        for (int mi = 0; mi < 2; ++mi) {
          const int row = wr * 32 + mi * 16 + (lane & 15);
          const int off = swz_off(row, kk, lane);
          ah[mi] = *(const half8*)(AH + off);
          al[mi] = *(const half8*)(AL + off);
        }
#pragma unroll
        for (int nf = 0; nf < 2; ++nf) {
          const int row = wc * 32 + nf * 16 + (lane & 15);
          const int off = swz_off(row, kk, lane);
          bv[nf] = *(const half8*)(BW + off);
        }
#pragma unroll
        for (int mi = 0; mi < 2; ++mi)
#pragma unroll
          for (int nf = 0; nf < 2; ++nf) {
            acc[mi][nf] = __builtin_amdgcn_mfma_f32_16x16x32_f16(ah[mi], bv[nf], acc[mi][nf], 0, 0, 0);
            acc[mi][nf] = __builtin_amdgcn_mfma_f32_16x16x32_f16(al[mi], bv[nf], acc[mi][nf], 0, 0, 0);
          }
      }
      __syncthreads();
      cur ^= 1;
    }
#undef STG

    float* C = inner + (size_t)(dG * 2 + kp) * B_ * NP;
#pragma unroll
    for (int mi = 0; mi < 2; ++mi)
#pragma unroll
      for (int nf = 0; nf < 2; ++nf) {
        const int gc = n0 + wc * 32 + nf * 16 + (lane & 15);
        const int gr = m0 + wr * 32 + mi * 16 + ((lane >> 4) << 2);
#pragma unroll
        for (int j = 0; j < 4; ++j)
          C[(size_t)(gr + j) * NP + gc] = acc[mi][nf][j];
      }
    return;
  }

  // ================= UPDATE part =================
  if (!doU) return;
  const int r = bid - GBLK;            // 0..127
  const int d = dU;
  const int srel = tU & (WIN - 1);

  const float* rec0 = inner + ((size_t)(d * 2 + 0) * B_ + r) * NP;
  const float* rec1 = inner + ((size_t)(d * 2 + 1) * B_ + r) * NP;
  const float* xr = xpw + ((size_t)(d * WIN + srel) * B_ + r) * NP;
  const float* rb = (d ? bw_bias : fw_bias) + N3;
  const float* g0 = d ? bw_ln0g : fw_ln0g;
  const float* b0 = d ? bw_ln0b : fw_ln0b;
  const float* g3 = d ? bw_ln3g : fw_ln3g;
  const float* b3 = d ? bw_ln3b : fw_ln3b;
  float* hl = hln + ((size_t)d * B_ + r) * U_;
  f16* hlbH = hlfH + ((size_t)d * B_ + r) * KU;
  f16* hlbL = hlfL + ((size_t)d * B_ + r) * KU;

  float zv[5], cv[5], hv[5];
  float s1 = 0.f, s2 = 0.f;
#pragma unroll
  for (int i = 0; i < 5; ++i) {
    const int c = tid + i * 256;
    if (c < U_) {
      const float z  = sigmf(xr[c] + rec0[c] + rec1[c] + rb[c]);
      const float rr = sigmf(xr[U_ + c] + rec0[U_ + c] + rec1[U_ + c] + rb[U_ + c]);
      const float cand = xr[2 * U_ + c] +
                         rr * (rec0[2 * U_ + c] + rec1[2 * U_ + c] + rb[2 * U_ + c]);
      zv[i] = z; cv[i] = cand;
      s1 += cand; s2 += cand * cand;
    }
  }
  breduce2(s1, s2, red, tid);
  const float m1 = s1 / U_;
  const float is1 = rsqrtf(s2 / U_ - m1 * m1 + LN_EPS);

  float t1 = 0.f, t2 = 0.f;
#pragma unroll
  for (int i = 0; i < 5; ++i) {
    const int c = tid + i * 256;
    if (c < U_) {
      const float hh = tanhf(g3[c] * (cv[i] - m1) * is1 + b3[c]);
      const float hn = zv[i] * hl[c] + (1.f - zv[i]) * hh;
      hv[i] = hn;
      t1 += hn; t2 += hn * hn;
    }
  }
  breduce2(t1, t2, red, tid);
  const float m2 = t1 / U_;
  const float is2 = rsqrtf(t2 / U_ - m2 * m2 + LN_EPS);

#pragma unroll
  for (int i = 0; i < 5; ++i) {
    const int c = tid + i * 256;
    if (c < U_) {
      const float hlnew = g0[c] * (hv[i] - m2) * is2 + b0[c];
      hl[c] = hlnew;
      const f16 hi = (f16)hlnew;
      hlbH[c] = hi;
      hlbL[c] = (f16)(hlnew - (float)hi);
      if (tU == T_ - 1) out_tv[(size_t)r * 2400 + (size_t)d * U_ + c] = hv[i];
    }
  }
}

// ---------------- host-side launch ----------------
extern "C" void kernel_launch(void* const* d_in, const int* in_sizes, int n_in,
                              void* d_out, int out_size, void* d_ws, size_t ws_size,
                              hipStream_t stream) {
  const int*   sent      = (const int*)  d_in[0];
  const float* embed     = (const float*)d_in[1];
  const float* fw_kernel = (const float*)d_in[2];
  const float* fw_rkern  = (const float*)d_in[3];
  const float* fw_bias   = (const float*)d_in[4];
  const float* fw_ln0g   = (const float*)d_in[5];
  const float* fw_ln0b   = (const float*)d_in[6];
  const float* fw_ln3g   = (const float*)d_in[7];
  const float* fw_ln3b   = (const float*)d_in[8];
  const float* bw_kernel = (const float*)d_in[9];
  const float* bw_rkern  = (const float*)d_in[10];
  const float* bw_bias   = (const float*)d_in[11];
  const float* bw_ln0g   = (const float*)d_in[12];
  const float* bw_ln0b   = (const float*)d_in[13];
  const float* bw_ln3g   = (const float*)d_in[14];
  const float* bw_ln3b   = (const float*)d_in[15];

  uint8_t* ws = (uint8_t*)d_ws;
  __hip_bfloat16* embH  = (__hip_bfloat16*)(ws + OFF_EMBH);
  __hip_bfloat16* embL  = (__hip_bfloat16*)(ws + OFF_EMBL);
  __hip_bfloat16* kTH   = (__hip_bfloat16*)(ws + OFF_KTH);
  __hip_bfloat16* kTL   = (__hip_bfloat16*)(ws + OFF_KTL);
  f16*            rkF   = (f16*)(ws + OFF_RKF);
  float*          xpw   = (float*)(ws + OFF_XPW);
  float*          inner = (float*)(ws + OFF_INNER);
  float*          hln   = (float*)(ws + OFF_HLN);
  f16*            hlfH  = (f16*)(ws + OFF_HLFH);
  f16*            hlfL  = (f16*)(ws + OFF_HLFL);

  float* out_tv  = (float*)d_out;                        // [128][2400]
  float* out_emb = (float*)d_out + (size_t)B_ * 2 * U_;  // [8192][620]

  // K1: embedding gather + tanh (fp32 + hi/lo bf16 planes)
  embed_kernel<<<B_ * T_, 256, 0, stream>>>(sent, embed, out_emb, embH, embL);

  // K2: weight transpose+cast — kernel: bf16 hi/lo; rkernel: single f16
  transpose_cast<<<dim3(NP / 32, KE / 32, 2), dim3(32, 8), 0, stream>>>(
      fw_kernel, bw_kernel, kTH, kTL, E_, KE);
  transpose_cast_f16<<<dim3(NP / 32, KU / 32, 2), dim3(32, 8), 0, stream>>>(
      fw_rkern, bw_rkern, rkF, U_, KU);

  // K4: h_ln = LN(0) = beta
  init_hln<<<(2 * B_ * KU + 255) / 256, 256, 0, stream>>>(fw_ln0b, bw_ln0b,
                                                          hln, hlfH, hlfL);

#define SF(dG_, doG_, dU_, tU_, doU_)                                          \
  step_fused<<<TBLK, 256, 0, stream>>>(                                        \
      rkF, hlfH, hlfL, hln, inner, xpw,                                        \
      fw_bias, bw_bias, fw_ln0g, fw_ln0b, fw_ln3g, fw_ln3b,                    \
      bw_ln0g, bw_ln0b, bw_ln3g, bw_ln3b, out_tv,                              \
      dG_, doG_, dU_, tU_, doU_)

  // staggered scan: A_t = {G d0@t || U d1@(t-1)}, [xwin at window starts],
  //                 B_t = {G d1@t || U d0@t}
  for (int t = 0; t < T_; ++t) {
    SF(0, 1, 1, t - 1, (t > 0) ? 1 : 0);
    if ((t & (WIN - 1)) == 0)
      xwin_gemm<<<928, 256, 0, stream>>>(
          embH, embL, kTH, kTL, fw_bias, bw_bias, xpw, t);
    SF(1, 1, 0, t, 1);
  }
  SF(0, 0, 1, T_ - 1, 1);   // final update for d1@63
#undef SF
}

// Round 10
// 1787.820 us; speedup vs baseline: 1.0583x; 1.0583x over previous
//
#include <hip/hip_runtime.h>
#include <hip/hip_bf16.h>

// Sizes
#define U_    1200
#define E_    620
#define B_    128
#define T_    64
#define N3    3600           // 3*U
#define NP    3712           // padded 3U = 29*128
#define KE    640            // padded E  = 10*64
#define KU    1216           // padded U  = 19*64
#define WIN   16             // xproj window (scan steps per window GEMM)
#define LN_EPS 1e-3f

#define GBLK  464            // GEMM blocks per launch (8 xcd-slots * 58)
#define UBLK  128            // update blocks per launch
#define TBLK  (GBLK + UBLK)  // 592

typedef __attribute__((ext_vector_type(8))) short short8;
typedef __attribute__((ext_vector_type(4))) float f32x4;
typedef _Float16 f16;
typedef __attribute__((ext_vector_type(8))) _Float16 half8;

// ---------------- workspace layout (bytes) ----------------
constexpr size_t OFF_EMBH  = 0;                                   // bf16 [8192][KE] hi
constexpr size_t SZ_EMB    = (size_t)8192 * KE * 2;
constexpr size_t OFF_EMBL  = OFF_EMBH + SZ_EMB;
constexpr size_t OFF_KTH   = OFF_EMBL + SZ_EMB;                   // bf16 [2][NP][KE] hi
constexpr size_t SZ_KT     = (size_t)2 * NP * KE * 2;
constexpr size_t OFF_KTL   = OFF_KTH + SZ_KT;
constexpr size_t OFF_RKF   = OFF_KTL + SZ_KT;                     // f16 [2][NP][KU]
constexpr size_t SZ_RKF    = (size_t)2 * NP * KU * 2;
constexpr size_t OFF_XPW   = OFF_RKF + SZ_RKF;                    // f32 [2][WIN][B][NP]
constexpr size_t SZ_XPW    = (size_t)2 * WIN * B_ * NP * 4;
constexpr size_t OFF_INNER = OFF_XPW + SZ_XPW;                    // f32 [2d*4kp][B][NP]
constexpr size_t SZ_INNER  = (size_t)8 * B_ * NP * 4;
constexpr size_t OFF_HLN   = OFF_INNER + SZ_INNER;                // f32 [2][B][U]
constexpr size_t SZ_HLN    = (size_t)2 * B_ * U_ * 4;
constexpr size_t OFF_HLFH  = OFF_HLN + SZ_HLN;                    // f16 [2][B][KU] hi
constexpr size_t SZ_HLF    = (size_t)2 * B_ * KU * 2;
constexpr size_t OFF_HLFL  = OFF_HLFH + SZ_HLF;

__device__ inline void lds_load16(const void* g, void* l) {
  __builtin_amdgcn_global_load_lds(
      (const __attribute__((address_space(1))) unsigned int*)g,
      (__attribute__((address_space(3))) unsigned int*)l, 16, 0, 0);
}

__device__ inline float sigmf(float x) { return 1.f / (1.f + expf(-x)); }

// Swizzle helpers (verified r6-r9: 0 bank conflicts). LDS tiles [rows][64
// 2B-elems]; stage pre-swizzles the GLOBAL column group, read XORs in-row.
__device__ inline int swz_scol(int tid) {
  return (((tid & 7) ^ ((tid >> 3) & 7)) << 3);
}
__device__ inline int swz_off(int row, int kk, int lane) {
  return row * 64 + ((kk * 32 + ((lane >> 4) << 3)) ^ ((row & 7) << 3));
}

// ---------------- K1: embedding gather + tanh (fp32 out + hi/lo bf16) -----
__global__ __launch_bounds__(256)
void embed_kernel(const int* __restrict__ sent, const float* __restrict__ embed,
                  float* __restrict__ out_emb,
                  __hip_bfloat16* __restrict__ embH, __hip_bfloat16* __restrict__ embL) {
  const int row = blockIdx.x;                 // b*T + t
  const int idx = sent[row];
  const float* src = embed + (size_t)idx * E_;
  for (int e = threadIdx.x; e < KE; e += 256) {
    float v = 0.f;
    if (e < E_) {
      v = tanhf(src[e]);
      out_emb[(size_t)row * E_ + e] = v;
    }
    const __hip_bfloat16 hi = __float2bfloat16(v);
    embH[(size_t)row * KE + e] = hi;
    embL[(size_t)row * KE + e] = __float2bfloat16(v - __bfloat162float(hi));
  }
}

// ---------------- K2a: transpose+cast [K][3600]f32 -> [NP][Kp] hi/lo bf16 --
__global__ __launch_bounds__(256)
void transpose_cast(const float* __restrict__ W0, const float* __restrict__ W1,
                    __hip_bfloat16* __restrict__ WtHi, __hip_bfloat16* __restrict__ WtLo,
                    int Kreal, int Kp) {
  const int d = blockIdx.z;
  const float* W = d ? W1 : W0;
  __hip_bfloat16* dstH = WtHi + (size_t)d * NP * Kp;
  __hip_bfloat16* dstL = WtLo + (size_t)d * NP * Kp;
  __shared__ float tile[32][33];
  const int n0 = blockIdx.x * 32, k0 = blockIdx.y * 32;
  const int tx = threadIdx.x, ty = threadIdx.y;   // 32 x 8
#pragma unroll
  for (int i = 0; i < 32; i += 8) {
    const int k = k0 + ty + i, n = n0 + tx;
    tile[ty + i][tx] = (k < Kreal && n < N3) ? W[(size_t)k * N3 + n] : 0.f;
  }
  __syncthreads();
#pragma unroll
  for (int i = 0; i < 32; i += 8) {
    const int n = n0 + ty + i, k = k0 + tx;
    const float v = tile[tx][ty + i];
    const __hip_bfloat16 hi = __float2bfloat16(v);
    dstH[(size_t)n * Kp + k] = hi;
    dstL[(size_t)n * Kp + k] = __float2bfloat16(v - __bfloat162float(hi));
  }
}

// ---------------- K2b: transpose+cast [K][3600]f32 -> [NP][Kp] f16 --------
__global__ __launch_bounds__(256)
void transpose_cast_f16(const float* __restrict__ W0, const float* __restrict__ W1,
                        f16* __restrict__ Wt, int Kreal, int Kp) {
  const int d = blockIdx.z;
  const float* W = d ? W1 : W0;
  f16* dst = Wt + (size_t)d * NP * Kp;
  __shared__ float tile[32][33];
  const int n0 = blockIdx.x * 32, k0 = blockIdx.y * 32;
  const int tx = threadIdx.x, ty = threadIdx.y;   // 32 x 8
#pragma unroll
  for (int i = 0; i < 32; i += 8) {
    const int k = k0 + ty + i, n = n0 + tx;
    tile[ty + i][tx] = (k < Kreal && n < N3) ? W[(size_t)k * N3 + n] : 0.f;
  }
  __syncthreads();
#pragma unroll
  for (int i = 0; i < 32; i += 8) {
    const int n = n0 + ty + i, k = k0 + tx;
    dst[(size_t)n * Kp + k] = (f16)tile[tx][ty + i];
  }
}

// ---------------- K4: init h_ln = LN(0) = beta ----------------
__global__ __launch_bounds__(256)
void init_hln(const float* __restrict__ fw_b0, const float* __restrict__ bw_b0,
              float* __restrict__ hln, f16* __restrict__ hlfH, f16* __restrict__ hlfL) {
  const int idx = blockIdx.x * 256 + threadIdx.x;   // [2*128*KU]
  if (idx >= 2 * B_ * KU) return;
  const int k = idx % KU;
  const int rowd = idx / KU;
  const int d = rowd >> 7;
  float v = 0.f;
  if (k < U_) {
    v = (d ? bw_b0 : fw_b0)[k];
    hln[(size_t)rowd * U_ + k] = v;
  }
  const f16 hi = (f16)v;
  hlfH[idx] = hi;
  hlfL[idx] = (f16)(v - (float)hi);
}

// ---------------- window GEMM: x+ib for WIN scan steps, f32 out -----------
// r8-proven structure: 2-barrier per K-step, 64 KB LDS, XCD-remapped,
// swizzled (0 conflicts). Only change vs r8: single f32 epilogue store.
__global__ __launch_bounds__(256)
void xwin_gemm(const __hip_bfloat16* __restrict__ embH, const __hip_bfloat16* __restrict__ embL,
               const __hip_bfloat16* __restrict__ kTH, const __hip_bfloat16* __restrict__ kTL,
               const float* __restrict__ fw_bias, const float* __restrict__ bw_bias,
               float* __restrict__ xpw, int w0) {
  constexpr int BM = 128, BN = 128, BK = 64;
  constexpr int WM = 64, WN = 64, FM = 4, FN = 4;
  constexpr int TA = BM * BK, TB = BN * BK;       // 8192 elems
  const int bid = blockIdx.x;
  const int w = (bid & 7) * 116 + (bid >> 3);     // bijective: 928 = 8*116
  const int d = w / 464;
  const int q = w % 464;
  const int nt = q / 16, mt = q % 16;
  const int m0 = mt * BM;
  const int n0 = nt * BN;

  const __hip_bfloat16* BH = kTH + (size_t)d * NP * KE;
  const __hip_bfloat16* BL = kTL + (size_t)d * NP * KE;

  const int tid = threadIdx.x;
  const int lane = tid & 63;
  const int wid = tid >> 6;
  const int wr = wid >> 1, wc = wid & 1;

  __shared__ __align__(16) __hip_bfloat16 As[2 * TA];
  __shared__ __align__(16) __hip_bfloat16 Bs[2 * TB];

  f32x4 acc[FM][FN] = {};

  const int srow = tid >> 3;
  const int scol = swz_scol(tid);

  for (int ks = 0; ks < KE / BK; ++ks) {
    const int k0 = ks * BK;
    __syncthreads();
#pragma unroll
    for (int it = 0; it < TA / 2048; ++it) {
      const int row = m0 + it * 32 + srow;       // m index
      const int b = row & 127, srel = row >> 7;
      const int txi = d ? (T_ - 1 - (w0 + srel)) : (w0 + srel);
      const size_t goff = (size_t)(b * T_ + txi) * KE + k0 + scol;
      lds_load16(embH + goff, As + it * 2048 + tid * 8);
      lds_load16(embL + goff, As + TA + it * 2048 + tid * 8);
    }
#pragma unroll
    for (int it = 0; it < TB / 2048; ++it) {
      const size_t goff = (size_t)(n0 + it * 32 + srow) * KE + k0 + scol;
      lds_load16(BH + goff, Bs + it * 2048 + tid * 8);
      lds_load16(BL + goff, Bs + TB + it * 2048 + tid * 8);
    }
    __syncthreads();
#pragma unroll
    for (int kk = 0; kk < BK / 32; ++kk) {
      short8 ah[FM], al[FM], bh[FN], bl[FN];
#pragma unroll
      for (int mi = 0; mi < FM; ++mi) {
        const int row = wr * WM + mi * 16 + (lane & 15);
        const int off = swz_off(row, kk, lane);
        ah[mi] = *(const short8*)(As + off);
        al[mi] = *(const short8*)(As + TA + off);
      }
#pragma unroll
      for (int ni = 0; ni < FN; ++ni) {
        const int row = wc * WN + ni * 16 + (lane & 15);
        const int off = swz_off(row, kk, lane);
        bh[ni] = *(const short8*)(Bs + off);
        bl[ni] = *(const short8*)(Bs + TB + off);
      }
#pragma unroll
      for (int mi = 0; mi < FM; ++mi)
#pragma unroll
        for (int ni = 0; ni < FN; ++ni) {
          acc[mi][ni] = __builtin_amdgcn_mfma_f32_16x16x32_bf16(ah[mi], bh[ni], acc[mi][ni], 0, 0, 0);
          acc[mi][ni] = __builtin_amdgcn_mfma_f32_16x16x32_bf16(ah[mi], bl[ni], acc[mi][ni], 0, 0, 0);
          acc[mi][ni] = __builtin_amdgcn_mfma_f32_16x16x32_bf16(al[mi], bh[ni], acc[mi][ni], 0, 0, 0);
        }
    }
  }

  const float* ib = d ? bw_bias : fw_bias;
#pragma unroll
  for (int mi = 0; mi < FM; ++mi)
#pragma unroll
    for (int ni = 0; ni < FN; ++ni) {
      const int gc = n0 + wc * WN + ni * 16 + (lane & 15);
      const float bv = (gc < N3) ? ib[gc] : 0.f;
      const int gr0 = m0 + wr * WM + mi * 16 + ((lane >> 4) << 2);
#pragma unroll
      for (int j = 0; j < 4; ++j) {
        const int gr = gr0 + j;
        const int b = gr & 127, srel = gr >> 7;
        const size_t off = ((size_t)(d * WIN + srel) * B_ + b) * NP + gc;
        xpw[off] = acc[mi][ni][j] + bv;
      }
    }
}

// ---------------- block-wide 2-value sum reduction ----------------
__device__ inline void breduce2(float& a, float& b, float* red, int tid) {
#pragma unroll
  for (int off = 32; off; off >>= 1) {
    a += __shfl_down(a, off, 64);
    b += __shfl_down(b, off, 64);
  }
  const int w = tid >> 6;
  __syncthreads();
  if ((tid & 63) == 0) { red[w] = a; red[4 + w] = b; }
  __syncthreads();
  a = red[0] + red[1] + red[2] + red[3];
  b = red[4] + red[5] + red[6] + red[7];
}

// ---------------- fused scan step: GEMM(dG,t) || UPDATE(dU,tU) ------------
// GEMM [0,464): rec = h_ln @ rkernel^T; A = f16 hi/lo (2 MFMA terms),
// W = f16 single (L2-resident, XCD-pinned: x=bid&7 -> (kp,m); each XCD's W
// quarter = 2.26 MB). split-K4: 5-step serial K-chain. T3 dbuf (24 KB x2,
// 3 blocks/CU). Update [464,592): other direction (dep crosses launches).
__global__ __launch_bounds__(256)
void step_fused(const f16* __restrict__ rkF,
                f16* __restrict__ hlfH, f16* __restrict__ hlfL,
                float* __restrict__ hln, float* __restrict__ inner,
                const float* __restrict__ xpw,
                const float* __restrict__ fw_bias, const float* __restrict__ bw_bias,
                const float* __restrict__ fw_ln0g, const float* __restrict__ fw_ln0b,
                const float* __restrict__ fw_ln3g, const float* __restrict__ fw_ln3b,
                const float* __restrict__ bw_ln0g, const float* __restrict__ bw_ln0b,
                const float* __restrict__ bw_ln3g, const float* __restrict__ bw_ln3b,
                float* __restrict__ out_tv,
                int dG, int doG, int dU, int tU, int doU) {
  // 2 bufs x {A hi 4096, A lo 4096, W 4096} f16 = 48 KB
  __shared__ __align__(16) f16 smem[24576];
  __shared__ float red[8];

  const int bid = blockIdx.x;
  const int tid = threadIdx.x;

  if (bid < GBLK) {
    // ================= GEMM part =================
    if (!doG) return;
    const int x  = bid & 7;            // ~xcd: (kp, m)
    const int kp = x >> 1;             // 0..3 K quarter
    const int m  = x & 1;
    const int nt = bid >> 3;           // 0..57
    const int ks0 = kp * 5;
    const int ks1 = (kp == 3) ? 19 : (ks0 + 5);
    const int m0 = m * 64;
    const int n0 = nt * 64;

    const int lane = tid & 63;
    const int wid = tid >> 6;
    const int wr = wid >> 1, wc = wid & 1;

    const f16* WF = rkF + (size_t)dG * NP * KU;

    f32x4 acc[2][2] = {};
    const int srow = tid >> 3;
    const int scol = swz_scol(tid);

#define STG(buf_, ks_)                                                         \
  {                                                                            \
    const int k0s = (ks_) * 64;                                                \
    f16* base = smem + (buf_) * 12288;                                         \
    _Pragma("unroll")                                                          \
    for (int it = 0; it < 2; ++it) {                                           \
      const size_t ga = (size_t)(dG * B_ + m0 + it * 32 + srow) * KU + k0s + scol; \
      lds_load16(hlfH + ga, base + it * 2048 + tid * 8);                       \
      lds_load16(hlfL + ga, base + 4096 + it * 2048 + tid * 8);                \
      const size_t gb = (size_t)(n0 + it * 32 + srow) * KU + k0s + scol;       \
      lds_load16(WF + gb, base + 8192 + it * 2048 + tid * 8);                  \
    }                                                                          \
  }

    STG(0, ks0)
    __syncthreads();
    int cur = 0;
    for (int ks = ks0; ks < ks1; ++ks) {
      if (ks + 1 < ks1) STG(cur ^ 1, ks + 1)
      const f16* AH = smem + cur * 12288;
      const f16* AL = AH + 4096;
      const f16* BW = AH + 8192;
#pragma unroll
      for (int kk = 0; kk < 2; ++kk) {
        half8 ah[2], al[2], bv[2];
#pragma unroll
        for (int mi = 0; mi < 2; ++mi) {
          const int row = wr * 32 + mi * 16 + (lane & 15);
          const int off = swz_off(row, kk, lane);
          ah[mi] = *(const half8*)(AH + off);
          al[mi] = *(const half8*)(AL + off);
        }
#pragma unroll
        for (int nf = 0; nf < 2; ++nf) {
          const int row = wc * 32 + nf * 16 + (lane & 15);
          const int off = swz_off(row, kk, lane);
          bv[nf] = *(const half8*)(BW + off);
        }
#pragma unroll
        for (int mi = 0; mi < 2; ++mi)
#pragma unroll
          for (int nf = 0; nf < 2; ++nf) {
            acc[mi][nf] = __builtin_amdgcn_mfma_f32_16x16x32_f16(ah[mi], bv[nf], acc[mi][nf], 0, 0, 0);
            acc[mi][nf] = __builtin_amdgcn_mfma_f32_16x16x32_f16(al[mi], bv[nf], acc[mi][nf], 0, 0, 0);
          }
      }
      __syncthreads();
      cur ^= 1;
    }
#undef STG

    float* C = inner + (size_t)(dG * 4 + kp) * B_ * NP;
#pragma unroll
    for (int mi = 0; mi < 2; ++mi)
#pragma unroll
      for (int nf = 0; nf < 2; ++nf) {
        const int gc = n0 + wc * 32 + nf * 16 + (lane & 15);
        const int gr = m0 + wr * 32 + mi * 16 + ((lane >> 4) << 2);
#pragma unroll
        for (int j = 0; j < 4; ++j)
          C[(size_t)(gr + j) * NP + gc] = acc[mi][nf][j];
      }
    return;
  }

  // ================= UPDATE part =================
  if (!doU) return;
  const int r = bid - GBLK;            // 0..127
  const int d = dU;
  const int srel = tU & (WIN - 1);

  const float* rec0 = inner + ((size_t)(d * 4 + 0) * B_ + r) * NP;
  const float* rec1 = inner + ((size_t)(d * 4 + 1) * B_ + r) * NP;
  const float* rec2 = inner + ((size_t)(d * 4 + 2) * B_ + r) * NP;
  const float* rec3 = inner + ((size_t)(d * 4 + 3) * B_ + r) * NP;
  const float* xr = xpw + ((size_t)(d * WIN + srel) * B_ + r) * NP;
  const float* rb = (d ? bw_bias : fw_bias) + N3;
  const float* g0 = d ? bw_ln0g : fw_ln0g;
  const float* b0 = d ? bw_ln0b : fw_ln0b;
  const float* g3 = d ? bw_ln3g : fw_ln3g;
  const float* b3 = d ? bw_ln3b : fw_ln3b;
  float* hl = hln + ((size_t)d * B_ + r) * U_;
  f16* hlbH = hlfH + ((size_t)d * B_ + r) * KU;
  f16* hlbL = hlfL + ((size_t)d * B_ + r) * KU;

  float zv[5], cv[5], hv[5];
  float s1 = 0.f, s2 = 0.f;
#pragma unroll
  for (int i = 0; i < 5; ++i) {
    const int c = tid + i * 256;
    if (c < U_) {
      const float rz = (rec0[c] + rec1[c]) + (rec2[c] + rec3[c]);
      const float rg = (rec0[U_ + c] + rec1[U_ + c]) + (rec2[U_ + c] + rec3[U_ + c]);
      const float rh = (rec0[2 * U_ + c] + rec1[2 * U_ + c]) + (rec2[2 * U_ + c] + rec3[2 * U_ + c]);
      const float z  = sigmf(xr[c] + rz + rb[c]);
      const float rr = sigmf(xr[U_ + c] + rg + rb[U_ + c]);
      const float cand = xr[2 * U_ + c] + rr * (rh + rb[2 * U_ + c]);
      zv[i] = z; cv[i] = cand;
      s1 += cand; s2 += cand * cand;
    }
  }
  breduce2(s1, s2, red, tid);
  const float m1 = s1 / U_;
  const float is1 = rsqrtf(s2 / U_ - m1 * m1 + LN_EPS);

  float t1 = 0.f, t2 = 0.f;
#pragma unroll
  for (int i = 0; i < 5; ++i) {
    const int c = tid + i * 256;
    if (c < U_) {
      const float hh = tanhf(g3[c] * (cv[i] - m1) * is1 + b3[c]);
      const float hn = zv[i] * hl[c] + (1.f - zv[i]) * hh;
      hv[i] = hn;
      t1 += hn; t2 += hn * hn;
    }
  }
  breduce2(t1, t2, red, tid);
  const float m2 = t1 / U_;
  const float is2 = rsqrtf(t2 / U_ - m2 * m2 + LN_EPS);

#pragma unroll
  for (int i = 0; i < 5; ++i) {
    const int c = tid + i * 256;
    if (c < U_) {
      const float hlnew = g0[c] * (hv[i] - m2) * is2 + b0[c];
      hl[c] = hlnew;
      const f16 hi = (f16)hlnew;
      hlbH[c] = hi;
      hlbL[c] = (f16)(hlnew - (float)hi);
      if (tU == T_ - 1) out_tv[(size_t)r * 2400 + (size_t)d * U_ + c] = hv[i];
    }
  }
}

// ---------------- host-side launch ----------------
extern "C" void kernel_launch(void* const* d_in, const int* in_sizes, int n_in,
                              void* d_out, int out_size, void* d_ws, size_t ws_size,
                              hipStream_t stream) {
  const int*   sent      = (const int*)  d_in[0];
  const float* embed     = (const float*)d_in[1];
  const float* fw_kernel = (const float*)d_in[2];
  const float* fw_rkern  = (const float*)d_in[3];
  const float* fw_bias   = (const float*)d_in[4];
  const float* fw_ln0g   = (const float*)d_in[5];
  const float* fw_ln0b   = (const float*)d_in[6];
  const float* fw_ln3g   = (const float*)d_in[7];
  const float* fw_ln3b   = (const float*)d_in[8];
  const float* bw_kernel = (const float*)d_in[9];
  const float* bw_rkern  = (const float*)d_in[10];
  const float* bw_bias   = (const float*)d_in[11];
  const float* bw_ln0g   = (const float*)d_in[12];
  const float* bw_ln0b   = (const float*)d_in[13];
  const float* bw_ln3g   = (const float*)d_in[14];
  const float* bw_ln3b   = (const float*)d_in[15];

  uint8_t* ws = (uint8_t*)d_ws;
  __hip_bfloat16* embH  = (__hip_bfloat16*)(ws + OFF_EMBH);
  __hip_bfloat16* embL  = (__hip_bfloat16*)(ws + OFF_EMBL);
  __hip_bfloat16* kTH   = (__hip_bfloat16*)(ws + OFF_KTH);
  __hip_bfloat16* kTL   = (__hip_bfloat16*)(ws + OFF_KTL);
  f16*            rkF   = (f16*)(ws + OFF_RKF);
  float*          xpw   = (float*)(ws + OFF_XPW);
  float*          inner = (float*)(ws + OFF_INNER);
  float*          hln   = (float*)(ws + OFF_HLN);
  f16*            hlfH  = (f16*)(ws + OFF_HLFH);
  f16*            hlfL  = (f16*)(ws + OFF_HLFL);

  float* out_tv  = (float*)d_out;                        // [128][2400]
  float* out_emb = (float*)d_out + (size_t)B_ * 2 * U_;  // [8192][620]

  // K1: embedding gather + tanh (fp32 + hi/lo bf16 planes)
  embed_kernel<<<B_ * T_, 256, 0, stream>>>(sent, embed, out_emb, embH, embL);

  // K2: weight transpose+cast — kernel: bf16 hi/lo; rkernel: single f16
  transpose_cast<<<dim3(NP / 32, KE / 32, 2), dim3(32, 8), 0, stream>>>(
      fw_kernel, bw_kernel, kTH, kTL, E_, KE);
  transpose_cast_f16<<<dim3(NP / 32, KU / 32, 2), dim3(32, 8), 0, stream>>>(
      fw_rkern, bw_rkern, rkF, U_, KU);

  // K4: h_ln = LN(0) = beta
  init_hln<<<(2 * B_ * KU + 255) / 256, 256, 0, stream>>>(fw_ln0b, bw_ln0b,
                                                          hln, hlfH, hlfL);

#define SF(dG_, doG_, dU_, tU_, doU_)                                          \
  step_fused<<<TBLK, 256, 0, stream>>>(                                        \
      rkF, hlfH, hlfL, hln, inner, xpw,                                        \
      fw_bias, bw_bias, fw_ln0g, fw_ln0b, fw_ln3g, fw_ln3b,                    \
      bw_ln0g, bw_ln0b, bw_ln3g, bw_ln3b, out_tv,                              \
      dG_, doG_, dU_, tU_, doU_)

  // staggered scan: A_t = {G d0@t || U d1@(t-1)}, [xwin at window starts],
  //                 B_t = {G d1@t || U d0@t}
  for (int t = 0; t < T_; ++t) {
    SF(0, 1, 1, t - 1, (t > 0) ? 1 : 0);
    if ((t & (WIN - 1)) == 0)
      xwin_gemm<<<928, 256, 0, stream>>>(
          embH, embL, kTH, kTL, fw_bias, bw_bias, xpw, t);
    SF(1, 1, 0, t, 1);
  }
  SF(0, 0, 1, T_ - 1, 1);   // final update for d1@63
#undef SF
}